// Round 2
// baseline (21.486 us; speedup 1.0000x reference)
//
#include <hip/hip_runtime.h>

// Problem constants (N=1)
#define LRES   64
#define ATOMS  14
#define M      896      // LRES*ATOMS
#define DF     128
#define HF     64
#define CUT2   25.0f    // 5.0^2

// One block per output element (a1,a2). 256 threads = 64 residues x 4 lanes.
// out[a1,a2] = sum_{i%14=a1} (si[i]+sb)*C[i][a2]  (row term)
//            + sum_{j%14=a2} sj[j]*C[j][a1]       (col term),  mut minus wt,
// where si = f·u, sj = f·v, u = W2@W1[:, :D], v = W2@W1[:, D:], sb = W2·b1,
// C[i][a] = #{masked partners of atom i with atom-slot a}.
__global__ __launch_bounds__(256) void k_fused(
    const float* __restrict__ feats_wt, const float* __restrict__ feats_mut,
    const float* __restrict__ pos_wt,   const float* __restrict__ pos_mut,
    const int* __restrict__ ppi_wt,     const int* __restrict__ ppi_mut,
    const float* __restrict__ W1, const float* __restrict__ b1,
    const float* __restrict__ W2, const float* __restrict__ b2,
    float* __restrict__ out)
{
    const int b  = blockIdx.x;          // 0..195
    const int a1 = b / ATOMS, a2 = b % ATOMS;
    const int t  = threadIdx.x;         // 0..255
    const int l1 = t >> 2;              // residue 0..63
    const int c  = t & 3;               // lane-within-residue 0..3

    __shared__ float u[DF], v[DF];
    __shared__ float sbs;
    __shared__ float part[LRES];

    // ---- phase 1: u, v (fold W2 into W1 halves), sb ----
    {
        const int d = t & 127;
        const float* col = W1 + ((t < 128) ? d : (DF + d));
        float s = 0.f;
        #pragma unroll 8
        for (int h = 0; h < HF; ++h) s += W2[h] * col[h * (2 * DF)];
        if (t < 128) u[d] = s; else v[d] = s;
    }
    if (t == 0) {
        float s = 0.f;
        #pragma unroll
        for (int h = 0; h < HF; ++h) s += W2[h] * b1[h];
        sbs = s;
    }

    // ---- phase 2: masked-partner counts (independent of u,v; no sync yet) ----
    const int i_row = l1 * ATOMS + a1;  // row-side atom (i % 14 == a1)
    const int j_col = l1 * ATOMS + a2;  // col-side atom (j % 14 == a2)
    const float rwx = pos_wt [i_row*3], rwy = pos_wt [i_row*3+1], rwz = pos_wt [i_row*3+2];
    const float rmx = pos_mut[i_row*3], rmy = pos_mut[i_row*3+1], rmz = pos_mut[i_row*3+2];
    const float cwx = pos_wt [j_col*3], cwy = pos_wt [j_col*3+1], cwz = pos_wt [j_col*3+2];
    const float cmx = pos_mut[j_col*3], cmy = pos_mut[j_col*3+1], cmz = pos_mut[j_col*3+2];
    const int codew = ppi_wt[l1], codem = ppi_mut[l1];

    int cw_r = 0, cm_r = 0, cw_c = 0, cm_c = 0;
    for (int l2 = c; l2 < LRES; l2 += 4) {
        const int jw = l2 * ATOMS + a2;     // row-side partner
        const int iw = l2 * ATOMS + a1;     // col-side partner
        if (ppi_wt[l2] != codew) {
            float dx = rwx - pos_wt[jw*3], dy = rwy - pos_wt[jw*3+1], dz = rwz - pos_wt[jw*3+2];
            if (dx*dx + dy*dy + dz*dz < CUT2) ++cw_r;
            dx = cwx - pos_wt[iw*3]; dy = cwy - pos_wt[iw*3+1]; dz = cwz - pos_wt[iw*3+2];
            if (dx*dx + dy*dy + dz*dz < CUT2) ++cw_c;
        }
        if (ppi_mut[l2] != codem) {
            float dx = rmx - pos_mut[jw*3], dy = rmy - pos_mut[jw*3+1], dz = rmz - pos_mut[jw*3+2];
            if (dx*dx + dy*dy + dz*dz < CUT2) ++cm_r;
            dx = cmx - pos_mut[iw*3]; dy = cmy - pos_mut[iw*3+1]; dz = cmz - pos_mut[iw*3+2];
            if (dx*dx + dy*dy + dz*dz < CUT2) ++cm_c;
        }
    }

    // ---- phase 3: per-atom dots (needs u,v) ----
    __syncthreads();
    float si_w = 0.f, si_m = 0.f, sj_w = 0.f, sj_m = 0.f;
    {
        const float4* fw_r = (const float4*)(feats_wt  + i_row * DF);
        const float4* fm_r = (const float4*)(feats_mut + i_row * DF);
        const float4* fw_c = (const float4*)(feats_wt  + j_col * DF);
        const float4* fm_c = (const float4*)(feats_mut + j_col * DF);
        const float4* u4 = (const float4*)u;
        const float4* v4 = (const float4*)v;
        #pragma unroll
        for (int q = c * 8; q < c * 8 + 8; ++q) {
            const float4 uu = u4[q], vv = v4[q];
            float4 a = fw_r[q];
            si_w += a.x*uu.x + a.y*uu.y + a.z*uu.z + a.w*uu.w;
            a = fm_r[q];
            si_m += a.x*uu.x + a.y*uu.y + a.z*uu.z + a.w*uu.w;
            a = fw_c[q];
            sj_w += a.x*vv.x + a.y*vv.y + a.z*vv.z + a.w*vv.w;
            a = fm_c[q];
            sj_m += a.x*vv.x + a.y*vv.y + a.z*vv.z + a.w*vv.w;
        }
    }

    // ---- reduce across the 4 lanes of each residue ----
    #pragma unroll
    for (int off = 2; off > 0; off >>= 1) {
        si_w += __shfl_down(si_w, off, 4);
        si_m += __shfl_down(si_m, off, 4);
        sj_w += __shfl_down(sj_w, off, 4);
        sj_m += __shfl_down(sj_m, off, 4);
        cw_r += __shfl_down(cw_r, off, 4);
        cm_r += __shfl_down(cm_r, off, 4);
        cw_c += __shfl_down(cw_c, off, 4);
        cm_c += __shfl_down(cm_c, off, 4);
    }
    if (c == 0) {
        const float sb = sbs;
        const float rowt = (si_m + sb) * (float)cm_r - (si_w + sb) * (float)cw_r;
        const float colt = sj_m * (float)cm_c - sj_w * (float)cw_c;
        part[l1] = rowt + colt;
    }
    __syncthreads();

    // ---- final fixed-order reduction ----
    if (t == 0) {
        float s = 0.f;
        #pragma unroll
        for (int k = 0; k < LRES; ++k) s += part[k];
        out[b] = s + b2[0];
    }
}

extern "C" void kernel_launch(void* const* d_in, const int* in_sizes, int n_in,
                              void* d_out, int out_size, void* d_ws, size_t ws_size,
                              hipStream_t stream) {
    const float* feats_wt  = (const float*)d_in[0];
    const float* feats_mut = (const float*)d_in[1];
    const float* pos_wt    = (const float*)d_in[2];   // (1,64,14,3) -> (896,3)
    const float* pos_mut   = (const float*)d_in[3];
    const int*   ppi_wt    = (const int*)d_in[4];     // (1,64)
    const int*   ppi_mut   = (const int*)d_in[5];
    const float* W1        = (const float*)d_in[6];   // (64, 256)
    const float* b1        = (const float*)d_in[7];   // (64,)
    const float* W2        = (const float*)d_in[8];   // (1, 64)
    const float* b2        = (const float*)d_in[9];   // (1,)
    float* out = (float*)d_out;                       // 196 floats

    k_fused<<<ATOMS * ATOMS, 256, 0, stream>>>(
        feats_wt, feats_mut, pos_wt, pos_mut, ppi_wt, ppi_mut,
        W1, b1, W2, b2, out);
}

// Round 3
// 18.153 us; speedup vs baseline: 1.1836x; 1.1836x over previous
//
#include <hip/hip_runtime.h>

// Problem constants (N=1)
#define LRES   64
#define ATOMS  14
#define M      896      // LRES*ATOMS
#define DF     128
#define HF     64
#define CUT2   25.0f    // 5.0^2

// One block per output element (a1,a2). 256 threads = 64 residues x 4 lanes.
// out[a1,a2] = sum_{i%14=a1} (si[i]+sb)*Cmask[i][a2]  (row term)
//            + sum_{j%14=a2} sj[j]*Cmask[j][a1]       (col term), mut minus wt,
// where si = f.u, sj = f.v, u = W2@W1[:, :D], v = W2@W1[:, D:], sb = W2.b1.
__global__ __launch_bounds__(256) void k_fused(
    const float* __restrict__ feats_wt, const float* __restrict__ feats_mut,
    const float* __restrict__ pos_wt,   const float* __restrict__ pos_mut,
    const int* __restrict__ ppi_wt,     const int* __restrict__ ppi_mut,
    const float* __restrict__ W1, const float* __restrict__ b1,
    const float* __restrict__ W2, const float* __restrict__ b2,
    float* __restrict__ out)
{
    const int b  = blockIdx.x;          // 0..195
    const int a1 = b / ATOMS, a2 = b % ATOMS;
    const int t  = threadIdx.x;         // 0..255

    __shared__ float u[DF], v[DF];
    __shared__ float pA[2][3][LRES];    // [wt/mut][xyz][l], atom slot a1
    __shared__ float pB[2][3][LRES];    // [wt/mut][xyz][l], atom slot a2
    __shared__ int   pp[2][LRES];
    __shared__ float part[LRES];
    __shared__ float sbs;

    // ---- stage positions (slots a1,a2 only) + chain codes into LDS ----
    {
        const int grp = t >> 6;         // 0: wt-a1, 1: wt-a2, 2: mut-a1, 3: mut-a2
        const int l   = t & 63;
        const int st  = grp >> 1;
        const int sl  = (grp & 1) ? a2 : a1;
        const float* ps = st ? pos_mut : pos_wt;
        const float* p  = ps + (l * ATOMS + sl) * 3;
        const float x = p[0], y = p[1], z = p[2];
        if (grp & 1) { pB[st][0][l] = x; pB[st][1][l] = y; pB[st][2][l] = z; }
        else         { pA[st][0][l] = x; pA[st][1][l] = y; pA[st][2][l] = z; }
        if (grp == 0) pp[0][l] = ppi_wt[l];
        if (grp == 1) pp[1][l] = ppi_mut[l];
    }

    // ---- u, v: fold W2 into W1 halves. Fully unrolled -> all loads in flight ----
    {
        const int d = t & 127;
        const float* col = W1 + d + ((t >> 7) ? DF : 0);
        float s = 0.f;
        #pragma unroll
        for (int h = 0; h < HF; ++h) s += W2[h] * col[h * (2 * DF)];
        if (t < 128) u[d] = s; else v[d] = s;
    }

    // ---- sb = W2.b1 on wave 0 (parallel + shuffle) ----
    if (t < 64) {
        float sbp = W2[t] * b1[t];
        #pragma unroll
        for (int off = 32; off > 0; off >>= 1) sbp += __shfl_down(sbp, off);
        if (t == 0) sbs = sbp;
    }

    __syncthreads();

    const int l1 = t >> 2;              // residue 0..63
    const int c  = t & 3;               // lane-within-residue
    const int i_row = l1 * ATOMS + a1;
    const int j_col = l1 * ATOMS + a2;

    // ---- masked-partner counts from LDS ----
    const int myw = pp[0][l1], mym = pp[1][l1];
    const float rwx = pA[0][0][l1], rwy = pA[0][1][l1], rwz = pA[0][2][l1];
    const float rmx = pA[1][0][l1], rmy = pA[1][1][l1], rmz = pA[1][2][l1];
    const float cwx = pB[0][0][l1], cwy = pB[0][1][l1], cwz = pB[0][2][l1];
    const float cmx = pB[1][0][l1], cmy = pB[1][1][l1], cmz = pB[1][2][l1];

    int cw_r = 0, cm_r = 0, cw_c = 0, cm_c = 0;
    #pragma unroll
    for (int k = 0; k < 16; ++k) {
        const int l2 = (k << 2) | c;
        if (pp[0][l2] != myw) {
            float dx = rwx - pB[0][0][l2], dy = rwy - pB[0][1][l2], dz = rwz - pB[0][2][l2];
            if (dx*dx + dy*dy + dz*dz < CUT2) ++cw_r;
            dx = cwx - pA[0][0][l2]; dy = cwy - pA[0][1][l2]; dz = cwz - pA[0][2][l2];
            if (dx*dx + dy*dy + dz*dz < CUT2) ++cw_c;
        }
        if (pp[1][l2] != mym) {
            float dx = rmx - pB[1][0][l2], dy = rmy - pB[1][1][l2], dz = rmz - pB[1][2][l2];
            if (dx*dx + dy*dy + dz*dz < CUT2) ++cm_r;
            dx = cmx - pA[1][0][l2]; dy = cmy - pA[1][1][l2]; dz = cmz - pA[1][2][l2];
            if (dx*dx + dy*dy + dz*dz < CUT2) ++cm_c;
        }
    }

    // ---- per-atom dots: f.u (rows) and f.v (cols), 32 floats per lane ----
    float si_w = 0.f, si_m = 0.f, sj_w = 0.f, sj_m = 0.f;
    {
        const float4* fw_r = (const float4*)(feats_wt  + i_row * DF);
        const float4* fm_r = (const float4*)(feats_mut + i_row * DF);
        const float4* fw_c = (const float4*)(feats_wt  + j_col * DF);
        const float4* fm_c = (const float4*)(feats_mut + j_col * DF);
        const float4* u4 = (const float4*)u;
        const float4* v4 = (const float4*)v;
        #pragma unroll
        for (int q = c * 8; q < c * 8 + 8; ++q) {
            const float4 uu = u4[q], vv = v4[q];
            float4 a = fw_r[q];
            si_w += a.x*uu.x + a.y*uu.y + a.z*uu.z + a.w*uu.w;
            a = fm_r[q];
            si_m += a.x*uu.x + a.y*uu.y + a.z*uu.z + a.w*uu.w;
            a = fw_c[q];
            sj_w += a.x*vv.x + a.y*vv.y + a.z*vv.z + a.w*vv.w;
            a = fm_c[q];
            sj_m += a.x*vv.x + a.y*vv.y + a.z*vv.z + a.w*vv.w;
        }
    }

    // ---- reduce across the 4 lanes of each residue ----
    #pragma unroll
    for (int off = 2; off > 0; off >>= 1) {
        si_w += __shfl_down(si_w, off, 4);
        si_m += __shfl_down(si_m, off, 4);
        sj_w += __shfl_down(sj_w, off, 4);
        sj_m += __shfl_down(sj_m, off, 4);
        cw_r += __shfl_down(cw_r, off, 4);
        cm_r += __shfl_down(cm_r, off, 4);
        cw_c += __shfl_down(cw_c, off, 4);
        cm_c += __shfl_down(cm_c, off, 4);
    }
    if (c == 0) {
        const float sb = sbs;
        part[l1] = (si_m + sb) * (float)cm_r - (si_w + sb) * (float)cw_r
                 +  sj_m * (float)cm_c       -  sj_w * (float)cw_c;
    }
    __syncthreads();

    // ---- final reduction on wave 0 ----
    if (t < 64) {
        float s = part[t];
        #pragma unroll
        for (int off = 32; off > 0; off >>= 1) s += __shfl_down(s, off);
        if (t == 0) out[b] = s + b2[0];
    }
}

extern "C" void kernel_launch(void* const* d_in, const int* in_sizes, int n_in,
                              void* d_out, int out_size, void* d_ws, size_t ws_size,
                              hipStream_t stream) {
    const float* feats_wt  = (const float*)d_in[0];
    const float* feats_mut = (const float*)d_in[1];
    const float* pos_wt    = (const float*)d_in[2];   // (1,64,14,3) -> (896,3)
    const float* pos_mut   = (const float*)d_in[3];
    const int*   ppi_wt    = (const int*)d_in[4];     // (1,64)
    const int*   ppi_mut   = (const int*)d_in[5];
    const float* W1        = (const float*)d_in[6];   // (64, 256)
    const float* b1        = (const float*)d_in[7];   // (64,)
    const float* W2        = (const float*)d_in[8];   // (1, 64)
    const float* b2        = (const float*)d_in[9];   // (1,)
    float* out = (float*)d_out;                       // 196 floats

    k_fused<<<ATOMS * ATOMS, 256, 0, stream>>>(
        feats_wt, feats_mut, pos_wt, pos_mut, ppi_wt, ppi_mut,
        W1, b1, W2, b2, out);
}

// Round 4
// 16.596 us; speedup vs baseline: 1.2946x; 1.0938x over previous
//
#include <hip/hip_runtime.h>

// Problem constants (N=1)
#define LRES   64
#define ATOMS  14
#define M      896      // LRES*ATOMS
#define DF     128
#define HF     64
#define CUT2   25.0f    // 5.0^2

// One block per output element (a1,a2). 256 threads = 64 residues x 4 lanes.
// out[a1,a2] = sum_{i%14=a1} (si[i]+sb)*Cmask[i][a2]  (row term)
//            + sum_{j%14=a2} sj[j]*Cmask[j][a1]       (col term), mut minus wt,
// where si = f.u, sj = f.v, u = W2@W1[:, :D], v = W2@W1[:, D:], sb = W2.b1.
__global__ __launch_bounds__(256) void k_fused(
    const float* __restrict__ feats_wt, const float* __restrict__ feats_mut,
    const float* __restrict__ pos_wt,   const float* __restrict__ pos_mut,
    const int* __restrict__ ppi_wt,     const int* __restrict__ ppi_mut,
    const float* __restrict__ W1, const float* __restrict__ b1,
    const float* __restrict__ W2, const float* __restrict__ b2,
    float* __restrict__ out)
{
    const int b  = blockIdx.x;          // 0..195
    const int a1 = b / ATOMS, a2 = b % ATOMS;
    const int t  = threadIdx.x;         // 0..255
    const int l1 = t >> 2;              // residue 0..63
    const int c  = t & 3;               // lane-within-residue
    const int i_row = l1 * ATOMS + a1;
    const int j_col = l1 * ATOMS + a2;

    __shared__ float u[DF], v[DF];
    __shared__ float pA[2][3][LRES];    // [wt/mut][xyz][l], atom slot a1
    __shared__ float pB[2][3][LRES];    // [wt/mut][xyz][l], atom slot a2
    __shared__ int   pp[2][LRES];
    __shared__ float part[LRES];
    __shared__ float sbs;

    // ---- prefetch row-side feats into registers (latency hidden by phases 1-2)
    float4 frw[4], frm[4];
    {
        const float4* fw_r = (const float4*)(feats_wt  + i_row * DF) + c * 8;
        const float4* fm_r = (const float4*)(feats_mut + i_row * DF) + c * 8;
        #pragma unroll
        for (int q = 0; q < 4; ++q) { frw[q] = fw_r[q]; frm[q] = fm_r[q]; }
        // second half loaded in phase 3 (keeps register pressure moderate)
    }

    // ---- stage positions (slots a1,a2 only) + chain codes into LDS ----
    {
        const int grp = t >> 6;         // 0: wt-a1, 1: wt-a2, 2: mut-a1, 3: mut-a2
        const int l   = t & 63;
        const int st  = grp >> 1;
        const int sl  = (grp & 1) ? a2 : a1;
        const float* ps = st ? pos_mut : pos_wt;
        const float* p  = ps + (l * ATOMS + sl) * 3;
        const float x = p[0], y = p[1], z = p[2];
        if (grp & 1) { pB[st][0][l] = x; pB[st][1][l] = y; pB[st][2][l] = z; }
        else         { pA[st][0][l] = x; pA[st][1][l] = y; pA[st][2][l] = z; }
        if (grp == 0) pp[0][l] = ppi_wt[l];
        if (grp == 1) pp[1][l] = ppi_mut[l];
    }

    // ---- u, v: fold W2 into W1 halves. 4 accumulators -> short FMA chains ----
    {
        const int d = t & 127;
        const float* col = W1 + d + ((t >> 7) ? DF : 0);
        float s0 = 0.f, s1 = 0.f, s2 = 0.f, s3 = 0.f;
        #pragma unroll
        for (int h = 0; h < HF; h += 4) {
            s0 += W2[h]     * col[(h)     * (2 * DF)];
            s1 += W2[h + 1] * col[(h + 1) * (2 * DF)];
            s2 += W2[h + 2] * col[(h + 2) * (2 * DF)];
            s3 += W2[h + 3] * col[(h + 3) * (2 * DF)];
        }
        const float s = (s0 + s1) + (s2 + s3);
        if (t < 128) u[d] = s; else v[d] = s;
    }

    // ---- sb = W2.b1 on wave 0 (parallel + shuffle) ----
    if (t < 64) {
        float sbp = W2[t] * b1[t];
        #pragma unroll
        for (int off = 32; off > 0; off >>= 1) sbp += __shfl_down(sbp, off);
        if (t == 0) sbs = sbp;
    }

    // ---- masked-partner counts from LDS (overlaps in-flight feats loads) ----
    const int myw = pp[0][l1], mym = pp[1][l1];
    const float rwx = pA[0][0][l1], rwy = pA[0][1][l1], rwz = pA[0][2][l1];
    const float rmx = pA[1][0][l1], rmy = pA[1][1][l1], rmz = pA[1][2][l1];
    const float cwx = pB[0][0][l1], cwy = pB[0][1][l1], cwz = pB[0][2][l1];
    const float cmx = pB[1][0][l1], cmy = pB[1][1][l1], cmz = pB[1][2][l1];
    // NOTE: LDS staging of pA/pB/pp happens in this same block's earlier phase
    // with no intervening barrier; but every LDS slot is written and read by
    // the SAME 64-residue pattern only after __syncthreads below? No -- the
    // counts read pp/pA/pB across lanes, so they must come after the barrier.
    int cw_r = 0, cm_r = 0, cw_c = 0, cm_c = 0;

    __syncthreads();

    #pragma unroll
    for (int k = 0; k < 16; ++k) {
        const int l2 = (k << 2) | c;
        if (pp[0][l2] != myw) {
            float dx = rwx - pB[0][0][l2], dy = rwy - pB[0][1][l2], dz = rwz - pB[0][2][l2];
            if (dx*dx + dy*dy + dz*dz < CUT2) ++cw_r;
            dx = cwx - pA[0][0][l2]; dy = cwy - pA[0][1][l2]; dz = cwz - pA[0][2][l2];
            if (dx*dx + dy*dy + dz*dz < CUT2) ++cw_c;
        }
        if (pp[1][l2] != mym) {
            float dx = rmx - pB[1][0][l2], dy = rmy - pB[1][1][l2], dz = rmz - pB[1][2][l2];
            if (dx*dx + dy*dy + dz*dz < CUT2) ++cm_r;
            dx = cmx - pA[1][0][l2]; dy = cmy - pA[1][1][l2]; dz = cmz - pA[1][2][l2];
            if (dx*dx + dy*dy + dz*dz < CUT2) ++cm_c;
        }
    }

    // ---- per-atom dots: f.u (rows) and f.v (cols), 32 floats per lane ----
    float si_w = 0.f, si_m = 0.f, sj_w = 0.f, sj_m = 0.f;
    {
        const float4* fw_r = (const float4*)(feats_wt  + i_row * DF) + c * 8;
        const float4* fm_r = (const float4*)(feats_mut + i_row * DF) + c * 8;
        const float4* fw_c = (const float4*)(feats_wt  + j_col * DF) + c * 8;
        const float4* fm_c = (const float4*)(feats_mut + j_col * DF) + c * 8;
        const float4* u4 = (const float4*)u + c * 8;
        const float4* v4 = (const float4*)v + c * 8;
        // prefetched first half (q=0..3)
        #pragma unroll
        for (int q = 0; q < 4; ++q) {
            const float4 uu = u4[q];
            si_w += frw[q].x*uu.x + frw[q].y*uu.y + frw[q].z*uu.z + frw[q].w*uu.w;
            si_m += frm[q].x*uu.x + frm[q].y*uu.y + frm[q].z*uu.z + frm[q].w*uu.w;
        }
        // second half + col-side
        #pragma unroll
        for (int q = 4; q < 8; ++q) {
            const float4 uu = u4[q];
            float4 a = fw_r[q];
            si_w += a.x*uu.x + a.y*uu.y + a.z*uu.z + a.w*uu.w;
            a = fm_r[q];
            si_m += a.x*uu.x + a.y*uu.y + a.z*uu.z + a.w*uu.w;
        }
        #pragma unroll
        for (int q = 0; q < 8; ++q) {
            const float4 vv = v4[q];
            float4 a = fw_c[q];
            sj_w += a.x*vv.x + a.y*vv.y + a.z*vv.z + a.w*vv.w;
            a = fm_c[q];
            sj_m += a.x*vv.x + a.y*vv.y + a.z*vv.z + a.w*vv.w;
        }
    }

    // ---- reduce across the 4 lanes of each residue ----
    #pragma unroll
    for (int off = 2; off > 0; off >>= 1) {
        si_w += __shfl_down(si_w, off, 4);
        si_m += __shfl_down(si_m, off, 4);
        sj_w += __shfl_down(sj_w, off, 4);
        sj_m += __shfl_down(sj_m, off, 4);
        cw_r += __shfl_down(cw_r, off, 4);
        cm_r += __shfl_down(cm_r, off, 4);
        cw_c += __shfl_down(cw_c, off, 4);
        cm_c += __shfl_down(cm_c, off, 4);
    }
    if (c == 0) {
        const float sb = sbs;
        part[l1] = (si_m + sb) * (float)cm_r - (si_w + sb) * (float)cw_r
                 +  sj_m * (float)cm_c       -  sj_w * (float)cw_c;
    }
    __syncthreads();

    // ---- final reduction on wave 0 ----
    if (t < 64) {
        float s = part[t];
        #pragma unroll
        for (int off = 32; off > 0; off >>= 1) s += __shfl_down(s, off);
        if (t == 0) out[b] = s + b2[0];
    }
}

extern "C" void kernel_launch(void* const* d_in, const int* in_sizes, int n_in,
                              void* d_out, int out_size, void* d_ws, size_t ws_size,
                              hipStream_t stream) {
    const float* feats_wt  = (const float*)d_in[0];
    const float* feats_mut = (const float*)d_in[1];
    const float* pos_wt    = (const float*)d_in[2];   // (1,64,14,3) -> (896,3)
    const float* pos_mut   = (const float*)d_in[3];
    const int*   ppi_wt    = (const int*)d_in[4];     // (1,64)
    const int*   ppi_mut   = (const int*)d_in[5];
    const float* W1        = (const float*)d_in[6];   // (64, 256)
    const float* b1        = (const float*)d_in[7];   // (64,)
    const float* W2        = (const float*)d_in[8];   // (1, 64)
    const float* b2        = (const float*)d_in[9];   // (1,)
    float* out = (float*)d_out;                       // 196 floats

    k_fused<<<ATOMS * ATOMS, 256, 0, stream>>>(
        feats_wt, feats_mut, pos_wt, pos_mut, ppi_wt, ppi_mut,
        W1, b1, W2, b2, out);
}

// Round 5
// 16.282 us; speedup vs baseline: 1.3196x; 1.0193x over previous
//
#include <hip/hip_runtime.h>

// Problem constants (N=1)
#define LRES   64
#define ATOMS  14
#define DF     128
#define HF     64
#define CUT2   25.0f    // 5.0^2

// One block per output element (a1,a2). 256 threads = 64 residues x 4 lanes.
// out[a1,a2] = sum_{i%14=a1} (si[i]+sb)*Cmask[i][a2]  (row term)
//            + sum_{j%14=a2} sj[j]*Cmask[j][a1]       (col term), mut minus wt,
// where si = f.u, sj = f.v, u = W2@W1[:, :D], v = W2@W1[:, D:], sb = W2.b1.
//
// Schedule: [prefetch all feats] [stage pos->LDS] [sb] barrier
//           [issue W1 loads | counts loop (LDS-only) | u/v fold] barrier
//           [dots from regs] [reduce]
// The W1 L2 pull (~64KB/block) hides behind the counts loop's VALU/LDS work.
__global__ __launch_bounds__(256) void k_fused(
    const float* __restrict__ feats_wt, const float* __restrict__ feats_mut,
    const float* __restrict__ pos_wt,   const float* __restrict__ pos_mut,
    const int* __restrict__ ppi_wt,     const int* __restrict__ ppi_mut,
    const float* __restrict__ W1, const float* __restrict__ b1,
    const float* __restrict__ W2, const float* __restrict__ b2,
    float* __restrict__ out)
{
    const int b  = blockIdx.x;          // 0..195
    const int a1 = b / ATOMS, a2 = b % ATOMS;
    const int t  = threadIdx.x;         // 0..255
    const int l1 = t >> 2;              // residue 0..63
    const int c  = t & 3;               // lane-within-residue
    const int i_row = l1 * ATOMS + a1;
    const int j_col = l1 * ATOMS + a2;

    __shared__ float4 posA[2][LRES];    // [wt/mut][res], atom slot a1 (xyz)
    __shared__ float4 posB[2][LRES];    // [wt/mut][res], atom slot a2 (xyz)
    __shared__ int    pp[2][LRES];
    __shared__ float4 uv4[2][4][9];     // u/v, padded: [u|v][c][q], stride 9
    __shared__ float  part[LRES];
    __shared__ float  sbs;

    // ---- prefetch ALL feats into registers (consumed in phase D) ----
    float4 frw[8], frm[8], fcw[8], fcm[8];
    {
        const float4* pfrw = (const float4*)(feats_wt  + i_row * DF) + c * 8;
        const float4* pfrm = (const float4*)(feats_mut + i_row * DF) + c * 8;
        const float4* pfcw = (const float4*)(feats_wt  + j_col * DF) + c * 8;
        const float4* pfcm = (const float4*)(feats_mut + j_col * DF) + c * 8;
        #pragma unroll
        for (int q = 0; q < 8; ++q) {
            frw[q] = pfrw[q]; frm[q] = pfrm[q];
            fcw[q] = pfcw[q]; fcm[q] = pfcm[q];
        }
    }

    // ---- stage positions (slots a1,a2 only) + chain codes into LDS ----
    {
        const int grp = t >> 6;         // 0: wt-a1, 1: wt-a2, 2: mut-a1, 3: mut-a2
        const int l   = t & 63;
        const int st  = grp >> 1;
        const int sl  = (grp & 1) ? a2 : a1;
        const float* ps = st ? pos_mut : pos_wt;
        const float* p  = ps + (l * ATOMS + sl) * 3;
        float4 q; q.x = p[0]; q.y = p[1]; q.z = p[2]; q.w = 0.f;
        if (grp & 1) posB[st][l] = q; else posA[st][l] = q;
        if (grp == 0) pp[0][l] = ppi_wt[l];
        if (grp == 1) pp[1][l] = ppi_mut[l];
    }

    // ---- sb = W2.b1 on wave 0 ----
    if (t < 64) {
        float sbp = W2[t] * b1[t];
        #pragma unroll
        for (int off = 32; off > 0; off >>= 1) sbp += __shfl_down(sbp, off);
        if (t == 0) sbs = sbp;
    }

    __syncthreads();

    // ---- phase B: issue W1 column loads (no barrier before their use) ----
    const int d = t & 127;
    const float* col = W1 + d + ((t >> 7) ? DF : 0);
    float w1v[HF];
    #pragma unroll
    for (int h = 0; h < HF; ++h) w1v[h] = col[h * (2 * DF)];

    // ---- counts loop: pure LDS/VALU, hides the W1 pull ----
    const float4 rw = posA[0][l1], rm = posA[1][l1];
    const float4 cw = posB[0][l1], cmv = posB[1][l1];
    const int myw = pp[0][l1], mym = pp[1][l1];
    int cw_r = 0, cm_r = 0, cw_c = 0, cm_c = 0;
    #pragma unroll
    for (int k = 0; k < 16; ++k) {
        const int l2 = (k << 2) | c;
        const int pw = pp[0][l2], pm = pp[1][l2];
        const float4 bw = posB[0][l2], aw = posA[0][l2];
        const float4 bm = posB[1][l2], am = posA[1][l2];
        if (pw != myw) {
            float dx = rw.x - bw.x, dy = rw.y - bw.y, dz = rw.z - bw.z;
            if (dx*dx + dy*dy + dz*dz < CUT2) ++cw_r;
            dx = cw.x - aw.x; dy = cw.y - aw.y; dz = cw.z - aw.z;
            if (dx*dx + dy*dy + dz*dz < CUT2) ++cw_c;
        }
        if (pm != mym) {
            float dx = rm.x - bm.x, dy = rm.y - bm.y, dz = rm.z - bm.z;
            if (dx*dx + dy*dy + dz*dz < CUT2) ++cm_r;
            dx = cmv.x - am.x; dy = cmv.y - am.y; dz = cmv.z - am.z;
            if (dx*dx + dy*dy + dz*dz < CUT2) ++cm_c;
        }
    }

    // ---- u/v fold: consume W1 loads (4 independent FMA chains) ----
    {
        float s0 = 0.f, s1 = 0.f, s2 = 0.f, s3 = 0.f;
        #pragma unroll
        for (int h = 0; h < HF; h += 4) {
            s0 += W2[h]     * w1v[h];
            s1 += W2[h + 1] * w1v[h + 1];
            s2 += W2[h + 2] * w1v[h + 2];
            s3 += W2[h + 3] * w1v[h + 3];
        }
        const float s = (s0 + s1) + (s2 + s3);
        float* up = (float*)&uv4[t >> 7][d >> 5][(d >> 2) & 7];
        up[d & 3] = s;
    }
    __syncthreads();

    // ---- phase D: dots entirely from registers + conflict-free u/v reads ----
    float si_w = 0.f, si_m = 0.f, sj_w = 0.f, sj_m = 0.f;
    #pragma unroll
    for (int q = 0; q < 8; ++q) {
        const float4 uu = uv4[0][c][q];
        const float4 vv = uv4[1][c][q];
        si_w += frw[q].x*uu.x + frw[q].y*uu.y + frw[q].z*uu.z + frw[q].w*uu.w;
        si_m += frm[q].x*uu.x + frm[q].y*uu.y + frm[q].z*uu.z + frm[q].w*uu.w;
        sj_w += fcw[q].x*vv.x + fcw[q].y*vv.y + fcw[q].z*vv.z + fcw[q].w*vv.w;
        sj_m += fcm[q].x*vv.x + fcm[q].y*vv.y + fcm[q].z*vv.z + fcm[q].w*vv.w;
    }

    // ---- reduce across the 4 lanes of each residue ----
    #pragma unroll
    for (int off = 2; off > 0; off >>= 1) {
        si_w += __shfl_down(si_w, off, 4);
        si_m += __shfl_down(si_m, off, 4);
        sj_w += __shfl_down(sj_w, off, 4);
        sj_m += __shfl_down(sj_m, off, 4);
        cw_r += __shfl_down(cw_r, off, 4);
        cm_r += __shfl_down(cm_r, off, 4);
        cw_c += __shfl_down(cw_c, off, 4);
        cm_c += __shfl_down(cm_c, off, 4);
    }
    if (c == 0) {
        const float sb = sbs;
        part[l1] = (si_m + sb) * (float)cm_r - (si_w + sb) * (float)cw_r
                 +  sj_m * (float)cm_c       -  sj_w * (float)cw_c;
    }
    __syncthreads();

    // ---- final reduction on wave 0 ----
    if (t < 64) {
        float s = part[t];
        #pragma unroll
        for (int off = 32; off > 0; off >>= 1) s += __shfl_down(s, off);
        if (t == 0) out[b] = s + b2[0];
    }
}

extern "C" void kernel_launch(void* const* d_in, const int* in_sizes, int n_in,
                              void* d_out, int out_size, void* d_ws, size_t ws_size,
                              hipStream_t stream) {
    const float* feats_wt  = (const float*)d_in[0];
    const float* feats_mut = (const float*)d_in[1];
    const float* pos_wt    = (const float*)d_in[2];   // (1,64,14,3) -> (896,3)
    const float* pos_mut   = (const float*)d_in[3];
    const int*   ppi_wt    = (const int*)d_in[4];     // (1,64)
    const int*   ppi_mut   = (const int*)d_in[5];
    const float* W1        = (const float*)d_in[6];   // (64, 256)
    const float* b1        = (const float*)d_in[7];   // (64,)
    const float* W2        = (const float*)d_in[8];   // (1, 64)
    const float* b2        = (const float*)d_in[9];   // (1,)
    float* out = (float*)d_out;                       // 196 floats

    k_fused<<<ATOMS * ATOMS, 256, 0, stream>>>(
        feats_wt, feats_mut, pos_wt, pos_mut, ppi_wt, ppi_mut,
        W1, b1, W2, b2, out);
}